// Round 3
// baseline (572.294 us; speedup 1.0000x reference)
//
#include <hip/hip_runtime.h>
#include <hip/hip_cooperative_groups.h>
#include <math.h>

namespace cg = cooperative_groups;

#define NB 4
#define NP 4096   // src points per batch
#define MP 4096   // tgt points per batch
#define NITER 10

// One fused cooperative kernel.
// Grid: 256 blocks (batch b = blk>>6, src-group g = blk&63), 512 threads
// (8 waves). All 8 waves own the SAME 64 src points (lane l -> point l);
// wave w scans tgt chunk [w*512, w*512+512) with broadcast LDS reads.
// Per iteration: scan -> cross-wave combine (LDS keys) -> wave-0 15-sum ->
// per-block partial row -> grid.sync -> every block redundantly reduces its
// batch's 64 rows (deterministic) + lane-0 double Kabsch -> update points in
// registers. Partials double-buffered by iteration parity (WAR safety).
__global__ __launch_bounds__(512, 2) void icp_fused(
        const float* __restrict__ src,
        const float* __restrict__ tgt,
        float* __restrict__ partials,     // [2][256][16] floats in ws
        float* __restrict__ out) {
    __shared__ float4 T[MP];              // 64 KB: tgt (x,y,z,|t|^2)
    __shared__ unsigned int CK[8 * 64];   // 2 KB: per-wave argmin keys
    __shared__ float RtL[12];             // R row-major (9) + t (3)

    cg::grid_group grid = cg::this_grid();

    const int blk = blockIdx.x;
    const int b   = blk >> 6;
    const int g   = blk & 63;
    const int tid = threadIdx.x;
    const int w   = tid >> 6;             // wave 0..7
    const int l   = tid & 63;
    const int gsrc = b * NP + g * 64 + l;

    // ---- one-time staging: batch b's tgt cloud -> LDS ----
    {
        const float* tb = tgt + b * MP * 3;
        for (int j = tid; j < MP; j += 512) {
            float x = tb[j * 3 + 0];
            float y = tb[j * 3 + 1];
            float z = tb[j * 3 + 2];
            T[j] = make_float4(x, y, z, x * x + y * y + z * z);
        }
    }
    // src point lives in registers for the whole kernel (same in all waves)
    float px = src[gsrc * 3 + 0];
    float py = src[gsrc * 3 + 1];
    float pz = src[gsrc * 3 + 2];
    __syncthreads();

    for (int it = 0; it < NITER; ++it) {
        // ---- NN scan: d = |s|^2 - 2 s.t + |t|^2 + 1 (>0 -> u32-orderable);
        // key = top-20-bit quantized d | 12-bit tgt index (first-min ties).
        const float nx = -2.0f * px, ny = -2.0f * py, nz = -2.0f * pz;
        const float sxx = px * px + py * py + pz * pz + 1.0f;
        const int m0 = w << 9;
        unsigned int best = 0xFFFFFFFFu;
        #pragma unroll 8
        for (int mm = 0; mm < 512; ++mm) {
            float4 t = T[m0 + mm];                 // broadcast read
            float d = fmaf(nx, t.x, fmaf(ny, t.y, fmaf(nz, t.z, t.w + sxx)));
            unsigned int key = (__float_as_uint(d) & 0xFFFFF000u) |
                               (unsigned int)(m0 + mm);
            best = best < key ? best : key;
        }
        CK[w * 64 + l] = best;
        __syncthreads();

        // ---- wave-0: combine 8 chunk winners, gather match, 15-sum ----
        if (w == 0) {
            unsigned int kb = CK[l];
            #pragma unroll
            for (int k = 1; k < 8; ++k) {
                unsigned int kk = CK[k * 64 + l];
                kb = kk < kb ? kk : kb;
            }
            float4 mt = T[kb & 0xFFFu];
            const float tx = mt.x, ty = mt.y, tz = mt.z;

            float v[15];
            v[0]  = px;      v[1]  = py;      v[2]  = pz;
            v[3]  = tx;      v[4]  = ty;      v[5]  = tz;
            v[6]  = px * tx; v[7]  = px * ty; v[8]  = px * tz;
            v[9]  = py * tx; v[10] = py * ty; v[11] = py * tz;
            v[12] = pz * tx; v[13] = pz * ty; v[14] = pz * tz;
            #pragma unroll
            for (int k = 0; k < 15; ++k) {
                float s = v[k];
                s += __shfl_down(s, 32);
                s += __shfl_down(s, 16);
                s += __shfl_down(s, 8);
                s += __shfl_down(s, 4);
                s += __shfl_down(s, 2);
                s += __shfl_down(s, 1);
                v[k] = s;
            }
            if (l == 0) {
                float* pp = partials + ((it & 1) * 256 + blk) * 16;
                #pragma unroll
                for (int k = 0; k < 15; ++k) pp[k] = v[k];
            }
        }

        grid.sync();   // partials from all blocks visible device-wide

        // ---- every block redundantly solves its batch's Kabsch ----
        if (w == 0) {
            const float* rowp = partials + ((it & 1) * 256 + b * 64 + l) * 16;
            double s[15];
            #pragma unroll
            for (int k = 0; k < 15; ++k) s[k] = (double)rowp[k];
            #pragma unroll
            for (int k = 0; k < 15; ++k) {
                double vv = s[k];
                vv += __shfl_down(vv, 32);
                vv += __shfl_down(vv, 16);
                vv += __shfl_down(vv, 8);
                vv += __shfl_down(vv, 4);
                vv += __shfl_down(vv, 2);
                vv += __shfl_down(vv, 1);
                s[k] = vv;
            }
            if (l == 0) {
                const double invN = 1.0 / (double)NP;
                double cs[3] = { s[0] * invN, s[1] * invN, s[2] * invN };
                double ct[3] = { s[3] * invN, s[4] * invN, s[5] * invN };
                double H[3][3];
                for (int d = 0; d < 3; ++d)
                    for (int e = 0; e < 3; ++e)
                        H[d][e] = s[6 + d * 3 + e] * invN - cs[d] * ct[e];

                double A[3][3];
                for (int i = 0; i < 3; ++i)
                    for (int j = 0; j < 3; ++j)
                        A[i][j] = H[0][i] * H[0][j] + H[1][i] * H[1][j] +
                                  H[2][i] * H[2][j];

                double V[3][3] = {{1, 0, 0}, {0, 1, 0}, {0, 0, 1}};
                for (int sweep = 0; sweep < 8; ++sweep) {
                    double off = A[0][1] * A[0][1] + A[0][2] * A[0][2] +
                                 A[1][2] * A[1][2];
                    if (off < 1e-30) break;
                    for (int pi = 0; pi < 3; ++pi) {
                        const int p = (pi == 2) ? 1 : 0;
                        const int q = (pi == 0) ? 1 : 2;
                        double apq = A[p][q];
                        if (apq == 0.0) continue;
                        double theta = (A[q][q] - A[p][p]) / (2.0 * apq);
                        double t = 1.0 / (fabs(theta) + sqrt(1.0 + theta * theta));
                        if (theta < 0.0) t = -t;
                        double cth = 1.0 / sqrt(1.0 + t * t);
                        double sth = t * cth;
                        double App = A[p][p], Aqq = A[q][q];
                        A[p][p] = App - t * apq;
                        A[q][q] = Aqq + t * apq;
                        A[p][q] = A[q][p] = 0.0;
                        const int r = 3 - p - q;
                        double Apr = A[p][r], Aqr = A[q][r];
                        A[p][r] = A[r][p] = cth * Apr - sth * Aqr;
                        A[q][r] = A[r][q] = sth * Apr + cth * Aqr;
                        for (int i = 0; i < 3; ++i) {
                            double Vip = V[i][p], Viq = V[i][q];
                            V[i][p] = cth * Vip - sth * Viq;
                            V[i][q] = sth * Vip + cth * Viq;
                        }
                    }
                }
                double lam[3] = { A[0][0], A[1][1], A[2][2] };
                for (int i = 0; i < 2; ++i)
                    for (int j = i + 1; j < 3; ++j)
                        if (lam[j] > lam[i]) {
                            double tl = lam[i]; lam[i] = lam[j]; lam[j] = tl;
                            for (int k = 0; k < 3; ++k) {
                                double tv = V[k][i]; V[k][i] = V[k][j]; V[k][j] = tv;
                            }
                        }

                double U[3][3];
                for (int k = 0; k < 3; ++k) {
                    double w0 = H[0][0] * V[0][k] + H[0][1] * V[1][k] + H[0][2] * V[2][k];
                    double w1 = H[1][0] * V[0][k] + H[1][1] * V[1][k] + H[1][2] * V[2][k];
                    double w2 = H[2][0] * V[0][k] + H[2][1] * V[1][k] + H[2][2] * V[2][k];
                    double nrm = sqrt(w0 * w0 + w1 * w1 + w2 * w2);
                    if (nrm > 1e-150) {
                        U[0][k] = w0 / nrm; U[1][k] = w1 / nrm; U[2][k] = w2 / nrm;
                    } else {
                        U[0][k] = U[1][0] * U[2][1] - U[2][0] * U[1][1];
                        U[1][k] = U[2][0] * U[0][1] - U[0][0] * U[2][1];
                        U[2][k] = U[0][0] * U[1][1] - U[1][0] * U[0][1];
                    }
                }

                double detH = H[0][0] * (H[1][1] * H[2][2] - H[1][2] * H[2][1])
                            - H[0][1] * (H[1][0] * H[2][2] - H[1][2] * H[2][0])
                            + H[0][2] * (H[1][0] * H[2][1] - H[1][1] * H[2][0]);
                double sgn = (detH < 0.0) ? -1.0 : 1.0;

                double R[3][3];
                for (int i = 0; i < 3; ++i)
                    for (int j = 0; j < 3; ++j)
                        R[i][j] = V[i][0] * U[j][0] + V[i][1] * U[j][1] +
                                  sgn * V[i][2] * U[j][2];
                double tv[3];
                for (int i = 0; i < 3; ++i)
                    tv[i] = ct[i] - (R[i][0] * cs[0] + R[i][1] * cs[1] +
                                     R[i][2] * cs[2]);

                for (int i = 0; i < 3; ++i)
                    for (int j = 0; j < 3; ++j)
                        RtL[i * 3 + j] = (float)R[i][j];
                for (int i = 0; i < 3; ++i)
                    RtL[9 + i] = (float)tv[i];
            }
        }
        __syncthreads();

        // ---- update points in registers: p <- p @ R + t ----
        {
            float x = px, y = py, z = pz;
            px = x * RtL[0] + y * RtL[3] + z * RtL[6] + RtL[9];
            py = x * RtL[1] + y * RtL[4] + z * RtL[7] + RtL[10];
            pz = x * RtL[2] + y * RtL[5] + z * RtL[8] + RtL[11];
        }
        // CK/RtL rewritten only after next iteration's __syncthreads/grid.sync
    }

    // ---- outputs: R [4,3,3], t [4,3], transformed_src [4,4096,3] ----
    if (w == 0) {
        out[48 + gsrc * 3 + 0] = px;
        out[48 + gsrc * 3 + 1] = py;
        out[48 + gsrc * 3 + 2] = pz;
    }
    if (g == 0 && tid < 9)  out[b * 9 + tid]      = RtL[tid];
    if (g == 0 && tid < 3)  out[36 + b * 3 + tid] = RtL[9 + tid];
}

extern "C" void kernel_launch(void* const* d_in, const int* in_sizes, int n_in,
                              void* d_out, int out_size, void* d_ws, size_t ws_size,
                              hipStream_t stream) {
    const float* src = (const float*)d_in[0];
    const float* tgt = (const float*)d_in[1];
    float* out      = (float*)d_out;
    float* partials = (float*)d_ws;    // 2*256*16 floats = 32 KB

    void* args[] = { (void*)&src, (void*)&tgt, (void*)&partials, (void*)&out };
    hipLaunchCooperativeKernel((void*)icp_fused, dim3(256), dim3(512),
                               args, 0, stream);
}

// Round 4
// 314.105 us; speedup vs baseline: 1.8220x; 1.8220x over previous
//
#include <hip/hip_runtime.h>
#include <math.h>

#define NB 4
#define NP 4096   // src points per batch
#define MP 4096   // tgt points per batch

// ---------------------------------------------------------------------------
// fp32 3x3 Kabsch from the 15 reduced sums (Σs, Σt, Σ s⊗t), lane-serial.
// s[0..2]=Σsrc, s[3..5]=Σtgt, s[6+3d+e]=Σ src_d*tgt_e.
// RtL out: R row-major [0..8], t [9..11]; transform is p' = p @ R + t.
// ---------------------------------------------------------------------------
__device__ __forceinline__ void kabsch_f32(const float* s, float* RtL) {
    const float invN = 1.0f / (float)NP;
    float cs[3] = { s[0] * invN, s[1] * invN, s[2] * invN };
    float ct[3] = { s[3] * invN, s[4] * invN, s[5] * invN };
    float H[3][3];
    for (int d = 0; d < 3; ++d)
        for (int e = 0; e < 3; ++e)
            H[d][e] = s[6 + d * 3 + e] * invN - cs[d] * ct[e];

    // A = H^T H, Jacobi eigendecomposition -> V, lam
    float A[3][3];
    for (int i = 0; i < 3; ++i)
        for (int j = 0; j < 3; ++j)
            A[i][j] = H[0][i] * H[0][j] + H[1][i] * H[1][j] + H[2][i] * H[2][j];

    float V[3][3] = {{1, 0, 0}, {0, 1, 0}, {0, 0, 1}};
    for (int sweep = 0; sweep < 10; ++sweep) {
        float off = A[0][1] * A[0][1] + A[0][2] * A[0][2] + A[1][2] * A[1][2];
        if (off < 1e-16f) break;
        for (int pi = 0; pi < 3; ++pi) {
            const int p = (pi == 2) ? 1 : 0;
            const int q = (pi == 0) ? 1 : 2;
            float apq = A[p][q];
            if (fabsf(apq) < 1e-30f) continue;
            float theta = (A[q][q] - A[p][p]) / (2.0f * apq);
            float t = 1.0f / (fabsf(theta) + sqrtf(1.0f + theta * theta));
            if (theta < 0.0f) t = -t;
            float cth = 1.0f / sqrtf(1.0f + t * t);
            float sth = t * cth;
            float App = A[p][p], Aqq = A[q][q];
            A[p][p] = App - t * apq;
            A[q][q] = Aqq + t * apq;
            A[p][q] = A[q][p] = 0.0f;
            const int r = 3 - p - q;
            float Apr = A[p][r], Aqr = A[q][r];
            A[p][r] = A[r][p] = cth * Apr - sth * Aqr;
            A[q][r] = A[r][q] = sth * Apr + cth * Aqr;
            for (int i = 0; i < 3; ++i) {
                float Vip = V[i][p], Viq = V[i][q];
                V[i][p] = cth * Vip - sth * Viq;
                V[i][q] = sth * Vip + cth * Viq;
            }
        }
    }
    float lam[3] = { A[0][0], A[1][1], A[2][2] };
    for (int i = 0; i < 2; ++i)
        for (int j = i + 1; j < 3; ++j)
            if (lam[j] > lam[i]) {
                float tl = lam[i]; lam[i] = lam[j]; lam[j] = tl;
                for (int k = 0; k < 3; ++k) {
                    float tv = V[k][i]; V[k][i] = V[k][j]; V[k][j] = tv;
                }
            }

    float U[3][3];
    for (int k = 0; k < 3; ++k) {
        float w0 = H[0][0] * V[0][k] + H[0][1] * V[1][k] + H[0][2] * V[2][k];
        float w1 = H[1][0] * V[0][k] + H[1][1] * V[1][k] + H[1][2] * V[2][k];
        float w2 = H[2][0] * V[0][k] + H[2][1] * V[1][k] + H[2][2] * V[2][k];
        float nrm = sqrtf(w0 * w0 + w1 * w1 + w2 * w2);
        if (nrm > 1e-20f) {
            U[0][k] = w0 / nrm; U[1][k] = w1 / nrm; U[2][k] = w2 / nrm;
        } else {
            U[0][k] = U[1][0] * U[2][1] - U[2][0] * U[1][1];
            U[1][k] = U[2][0] * U[0][1] - U[0][0] * U[2][1];
            U[2][k] = U[0][0] * U[1][1] - U[1][0] * U[0][1];
        }
    }

    float detH = H[0][0] * (H[1][1] * H[2][2] - H[1][2] * H[2][1])
               - H[0][1] * (H[1][0] * H[2][2] - H[1][2] * H[2][0])
               + H[0][2] * (H[1][0] * H[2][1] - H[1][1] * H[2][0]);
    float sgn = (detH < 0.0f) ? -1.0f : 1.0f;

    float R[3][3];
    for (int i = 0; i < 3; ++i)
        for (int j = 0; j < 3; ++j)
            R[i][j] = V[i][0] * U[j][0] + V[i][1] * U[j][1] + sgn * V[i][2] * U[j][2];
    float tv[3];
    for (int i = 0; i < 3; ++i)
        tv[i] = ct[i] - (R[i][0] * cs[0] + R[i][1] * cs[1] + R[i][2] * cs[2]);

    for (int i = 0; i < 3; ++i)
        for (int j = 0; j < 3; ++j)
            RtL[i * 3 + j] = R[i][j];
    for (int i = 0; i < 3; ++i) RtL[9 + i] = tv[i];
}

// ---------------------------------------------------------------------------
// One ICP iteration per dispatch. 256 blocks (batch b = blk>>6, src-group
// g = blk&63), 512 threads (8 waves), all waves own the same 64 src points.
// Prologue: waves 1-7 stage tgt -> LDS as (-2x,-2y,-2z,|t|^2) while wave 0
// redundantly solves the PREVIOUS iteration's (R,t) from its batch's 64
// partial rows (fp32 Kabsch; identity if first). Then all threads transform
// their point, wave w scans chunk [w*512, w*512+512) with broadcast LDS
// reads, cross-wave combine via CK keys, wave-0 15-sum -> partials_out row.
// Kernel boundary = the device-wide barrier (no grid.sync).
// ---------------------------------------------------------------------------
__global__ __launch_bounds__(512, 2) void icp_scan(
        const float* __restrict__ src,
        const float* __restrict__ tgt,
        float* __restrict__ S,            // [NB*NP*3] transformed points
        const float* __restrict__ pprev,  // [256][16] prev partials (unused if first)
        float* __restrict__ pout,         // [256][16] this iteration's partials
        int first) {
    __shared__ float4 T[MP];              // 64 KB
    __shared__ unsigned int CK[512];      // per-wave argmin keys
    __shared__ float RtL[12];

    const int blk = blockIdx.x;
    const int b   = blk >> 6;
    const int g   = blk & 63;
    const int tid = threadIdx.x;
    const int w   = tid >> 6;
    const int l   = tid & 63;
    const int gsrc = b * NP + g * 64 + l;

    if (w != 0) {
        // waves 1-7: stage tgt tile (pre-negated) while wave 0 solves
        const float* tb = tgt + b * MP * 3;
        for (int j = tid - 64; j < MP; j += 448) {
            float x = tb[j * 3 + 0];
            float y = tb[j * 3 + 1];
            float z = tb[j * 3 + 2];
            T[j] = make_float4(-2.0f * x, -2.0f * y, -2.0f * z,
                               x * x + y * y + z * z);
        }
    } else {
        if (first) {
            if (l < 12) RtL[l] = (l == 0 || l == 4 || l == 8) ? 1.0f : 0.0f;
        } else {
            const float4* rp = (const float4*)(pprev + (b * 64 + l) * 16);
            float4 r0 = rp[0], r1 = rp[1], r2 = rp[2], r3 = rp[3];
            float sm[15] = { r0.x, r0.y, r0.z, r0.w, r1.x, r1.y, r1.z, r1.w,
                             r2.x, r2.y, r2.z, r2.w, r3.x, r3.y, r3.z };
            #pragma unroll
            for (int k = 0; k < 15; ++k) {
                float v = sm[k];
                v += __shfl_down(v, 32);
                v += __shfl_down(v, 16);
                v += __shfl_down(v, 8);
                v += __shfl_down(v, 4);
                v += __shfl_down(v, 2);
                v += __shfl_down(v, 1);
                sm[k] = v;
            }
            if (l == 0) kabsch_f32(sm, RtL);
        }
    }
    __syncthreads();

    // transform own point with the just-solved (R,t); persist for next iter
    float px, py, pz;
    {
        const float* P = first ? src : S;
        float x = P[gsrc * 3 + 0];
        float y = P[gsrc * 3 + 1];
        float z = P[gsrc * 3 + 2];
        px = x * RtL[0] + y * RtL[3] + z * RtL[6] + RtL[9];
        py = x * RtL[1] + y * RtL[4] + z * RtL[7] + RtL[10];
        pz = x * RtL[2] + y * RtL[5] + z * RtL[8] + RtL[11];
    }
    if (w == 0) {
        S[gsrc * 3 + 0] = px;
        S[gsrc * 3 + 1] = py;
        S[gsrc * 3 + 2] = pz;
    }

    // NN scan: d = |s|^2+1 - 2 s.t + |t|^2 (>0, u32-orderable); key packs
    // top-20-bit quantized d with the 12-bit tgt index (first-min on ties).
    const float sxx1 = px * px + py * py + pz * pz + 1.0f;
    const int m0 = w << 9;
    unsigned int best = 0xFFFFFFFFu;
    #pragma unroll 8
    for (int mm = 0; mm < 512; ++mm) {
        float4 t = T[m0 + mm];                    // broadcast read
        float d = fmaf(px, t.x, fmaf(py, t.y, fmaf(pz, t.z, t.w + sxx1)));
        unsigned int key = (__float_as_uint(d) & 0xFFFFF000u) |
                           (unsigned int)(m0 + mm);
        best = best < key ? best : key;
    }
    CK[w * 64 + l] = best;
    __syncthreads();

    if (w == 0) {
        unsigned int kb = CK[l];
        #pragma unroll
        for (int k = 1; k < 8; ++k) {
            unsigned int kk = CK[k * 64 + l];
            kb = kk < kb ? kk : kb;
        }
        float4 mt = T[kb & 0xFFFu];
        const float tx = -0.5f * mt.x;            // undo the -2x staging (exact)
        const float ty = -0.5f * mt.y;
        const float tz = -0.5f * mt.z;

        float v[15];
        v[0]  = px;      v[1]  = py;      v[2]  = pz;
        v[3]  = tx;      v[4]  = ty;      v[5]  = tz;
        v[6]  = px * tx; v[7]  = px * ty; v[8]  = px * tz;
        v[9]  = py * tx; v[10] = py * ty; v[11] = py * tz;
        v[12] = pz * tx; v[13] = pz * ty; v[14] = pz * tz;
        #pragma unroll
        for (int k = 0; k < 15; ++k) {
            float s = v[k];
            s += __shfl_down(s, 32);
            s += __shfl_down(s, 16);
            s += __shfl_down(s, 8);
            s += __shfl_down(s, 4);
            s += __shfl_down(s, 2);
            s += __shfl_down(s, 1);
            v[k] = s;
        }
        if (l == 0) {
            float* pp = pout + blk * 16;
            #pragma unroll
            for (int k = 0; k < 15; ++k) pp[k] = v[k];
        }
    }
}

// Final: solve iteration-10's (R,t) (redundant per block), apply, write out.
// out layout: R [4,3,3] flat (36), t [4,3] flat (12), points [4,4096,3].
__global__ __launch_bounds__(256) void icp_final(
        const float* __restrict__ S,
        const float* __restrict__ plast,
        float* __restrict__ out) {
    __shared__ float RtL[12];
    const int bk  = blockIdx.x;
    const int tid = threadIdx.x;
    const int gid = bk * 256 + tid;               // 0..16383
    const int b   = gid >> 12;

    if (tid < 64) {
        const float4* rp = (const float4*)(plast + (b * 64 + tid) * 16);
        float4 r0 = rp[0], r1 = rp[1], r2 = rp[2], r3 = rp[3];
        float sm[15] = { r0.x, r0.y, r0.z, r0.w, r1.x, r1.y, r1.z, r1.w,
                         r2.x, r2.y, r2.z, r2.w, r3.x, r3.y, r3.z };
        #pragma unroll
        for (int k = 0; k < 15; ++k) {
            float v = sm[k];
            v += __shfl_down(v, 32);
            v += __shfl_down(v, 16);
            v += __shfl_down(v, 8);
            v += __shfl_down(v, 4);
            v += __shfl_down(v, 2);
            v += __shfl_down(v, 1);
            sm[k] = v;
        }
        if (tid == 0) kabsch_f32(sm, RtL);
    }
    __syncthreads();

    float x = S[gid * 3 + 0];
    float y = S[gid * 3 + 1];
    float z = S[gid * 3 + 2];
    out[48 + gid * 3 + 0] = x * RtL[0] + y * RtL[3] + z * RtL[6] + RtL[9];
    out[48 + gid * 3 + 1] = x * RtL[1] + y * RtL[4] + z * RtL[7] + RtL[10];
    out[48 + gid * 3 + 2] = x * RtL[2] + y * RtL[5] + z * RtL[8] + RtL[11];
    if ((bk & 15) == 0) {
        if (tid < 9) out[b * 9 + tid] = RtL[tid];
        if (tid < 3) out[36 + b * 3 + tid] = RtL[9 + tid];
    }
}

extern "C" void kernel_launch(void* const* d_in, const int* in_sizes, int n_in,
                              void* d_out, int out_size, void* d_ws, size_t ws_size,
                              hipStream_t stream) {
    const float* src = (const float*)d_in[0];
    const float* tgt = (const float*)d_in[1];
    float* out = (float*)d_out;

    float* W  = (float*)d_ws;
    float* S  = W;                 // 49152 floats
    float* pA = W + 49152;         // 4096 floats (256 rows x 16)
    float* pB = pA + 4096;         // 4096 floats
    float* bufs[2] = { pA, pB };

    for (int k = 0; k < 10; ++k) {
        icp_scan<<<256, 512, 0, stream>>>(src, tgt, S,
                                          bufs[(k + 1) & 1], bufs[k & 1],
                                          k == 0 ? 1 : 0);
    }
    icp_final<<<64, 256, 0, stream>>>(S, bufs[1], out);
}

// Round 5
// 254.628 us; speedup vs baseline: 2.2476x; 1.2336x over previous
//
#include <hip/hip_runtime.h>
#include <math.h>

#define NB 4
#define NP 4096   // src points per batch
#define MP 4096   // tgt points per batch

typedef float f32x16 __attribute__((ext_vector_type(16)));

// issue one 64 B scalar load (4 tgt points) into a 16-SGPR tuple
#define ISSUE(B, P) asm volatile("s_load_dwordx16 %0, %1, 0x0" \
                                 : "=s"(B) : "s"(P))
// wait until <=N scalar loads outstanding; tie to B so consumption can't hoist
#define SWAIT(B, N) asm volatile("s_waitcnt lgkmcnt(" #N ")" : "+s"(B))

// ---------------------------------------------------------------------------
// fp32 3x3 Kabsch from the 15 reduced sums (identical to R4).
// ---------------------------------------------------------------------------
__device__ __forceinline__ void kabsch_f32(const float* s, float* RtL) {
    const float invN = 1.0f / (float)NP;
    float cs[3] = { s[0] * invN, s[1] * invN, s[2] * invN };
    float ct[3] = { s[3] * invN, s[4] * invN, s[5] * invN };
    float H[3][3];
    for (int d = 0; d < 3; ++d)
        for (int e = 0; e < 3; ++e)
            H[d][e] = s[6 + d * 3 + e] * invN - cs[d] * ct[e];

    float A[3][3];
    for (int i = 0; i < 3; ++i)
        for (int j = 0; j < 3; ++j)
            A[i][j] = H[0][i] * H[0][j] + H[1][i] * H[1][j] + H[2][i] * H[2][j];

    float V[3][3] = {{1, 0, 0}, {0, 1, 0}, {0, 0, 1}};
    for (int sweep = 0; sweep < 10; ++sweep) {
        float off = A[0][1] * A[0][1] + A[0][2] * A[0][2] + A[1][2] * A[1][2];
        if (off < 1e-16f) break;
        for (int pi = 0; pi < 3; ++pi) {
            const int p = (pi == 2) ? 1 : 0;
            const int q = (pi == 0) ? 1 : 2;
            float apq = A[p][q];
            if (fabsf(apq) < 1e-30f) continue;
            float theta = (A[q][q] - A[p][p]) / (2.0f * apq);
            float t = 1.0f / (fabsf(theta) + sqrtf(1.0f + theta * theta));
            if (theta < 0.0f) t = -t;
            float cth = 1.0f / sqrtf(1.0f + t * t);
            float sth = t * cth;
            float App = A[p][p], Aqq = A[q][q];
            A[p][p] = App - t * apq;
            A[q][q] = Aqq + t * apq;
            A[p][q] = A[q][p] = 0.0f;
            const int r = 3 - p - q;
            float Apr = A[p][r], Aqr = A[q][r];
            A[p][r] = A[r][p] = cth * Apr - sth * Aqr;
            A[q][r] = A[r][q] = sth * Apr + cth * Aqr;
            for (int i = 0; i < 3; ++i) {
                float Vip = V[i][p], Viq = V[i][q];
                V[i][p] = cth * Vip - sth * Viq;
                V[i][q] = sth * Vip + cth * Viq;
            }
        }
    }
    float lam[3] = { A[0][0], A[1][1], A[2][2] };
    for (int i = 0; i < 2; ++i)
        for (int j = i + 1; j < 3; ++j)
            if (lam[j] > lam[i]) {
                float tl = lam[i]; lam[i] = lam[j]; lam[j] = tl;
                for (int k = 0; k < 3; ++k) {
                    float tv = V[k][i]; V[k][i] = V[k][j]; V[k][j] = tv;
                }
            }

    float U[3][3];
    for (int k = 0; k < 3; ++k) {
        float w0 = H[0][0] * V[0][k] + H[0][1] * V[1][k] + H[0][2] * V[2][k];
        float w1 = H[1][0] * V[0][k] + H[1][1] * V[1][k] + H[1][2] * V[2][k];
        float w2 = H[2][0] * V[0][k] + H[2][1] * V[1][k] + H[2][2] * V[2][k];
        float nrm = sqrtf(w0 * w0 + w1 * w1 + w2 * w2);
        if (nrm > 1e-20f) {
            U[0][k] = w0 / nrm; U[1][k] = w1 / nrm; U[2][k] = w2 / nrm;
        } else {
            U[0][k] = U[1][0] * U[2][1] - U[2][0] * U[1][1];
            U[1][k] = U[2][0] * U[0][1] - U[0][0] * U[2][1];
            U[2][k] = U[0][0] * U[1][1] - U[1][0] * U[0][1];
        }
    }

    float detH = H[0][0] * (H[1][1] * H[2][2] - H[1][2] * H[2][1])
               - H[0][1] * (H[1][0] * H[2][2] - H[1][2] * H[2][0])
               + H[0][2] * (H[1][0] * H[2][1] - H[1][1] * H[2][0]);
    float sgn = (detH < 0.0f) ? -1.0f : 1.0f;

    float R[3][3];
    for (int i = 0; i < 3; ++i)
        for (int j = 0; j < 3; ++j)
            R[i][j] = V[i][0] * U[j][0] + V[i][1] * U[j][1] + sgn * V[i][2] * U[j][2];
    float tv[3];
    for (int i = 0; i < 3; ++i)
        tv[i] = ct[i] - (R[i][0] * cs[0] + R[i][1] * cs[1] + R[i][2] * cs[2]);

    for (int i = 0; i < 3; ++i)
        for (int j = 0; j < 3; ++j)
            RtL[i * 3 + j] = R[i][j];
    for (int i = 0; i < 3; ++i) RtL[9 + i] = tv[i];
}

__global__ __launch_bounds__(256) void init_tgt(const float* __restrict__ tgt,
                                                float4* __restrict__ tgt4) {
    int j = blockIdx.x * 256 + threadIdx.x;       // 0..16383
    float x = tgt[j * 3 + 0];
    float y = tgt[j * 3 + 1];
    float z = tgt[j * 3 + 2];
    tgt4[j] = make_float4(x, y, z, x * x + y * y + z * z);
}

// ---------------------------------------------------------------------------
// One ICP iteration per dispatch. 256 blocks (batch b = blk>>6, src-group
// g = blk&63), 512 threads (8 waves); lane l of every wave owns src point l
// of the group; wave w scans tgt chunk [w*512, w*512+512).
// tgt chunk is streamed through 3 rotating 16-SGPR buffers via
// s_load_dwordx16 (wave-uniform data -> scalar pipe; ZERO LDS in the loop,
// SGPR operands fold into the VALU fmas). Prefetch is issued before the
// prologue barrier so the loads overlap the redundant fp32 Kabsch solve.
// ---------------------------------------------------------------------------
__global__ __launch_bounds__(512) void icp_scan(
        const float* __restrict__ src,
        const float4* __restrict__ tgt4,
        float* __restrict__ S,            // [NB*NP*3] transformed points
        const float* __restrict__ pprev,  // [256][16] prev partials
        float* __restrict__ pout,         // [256][16] this iter's partials
        int first) {
    __shared__ unsigned int CK[512];
    __shared__ float RtL[12];

    const int blk = blockIdx.x;
    const int b   = blk >> 6;
    const int g   = blk & 63;
    const int tid = threadIdx.x;
    const int w   = tid >> 6;
    const int l   = tid & 63;
    const int gsrc = b * NP + g * 64 + l;

    // wave-uniform base of this wave's 512-point chunk (bytes)
    const float4* tb4 = tgt4 + b * MP;
    unsigned chunkOff = __builtin_amdgcn_readfirstlane((unsigned)(w << 9) * 16u);
    const char* pb = (const char*)tb4 + chunkOff;

    // prefetch the first 3 groups (4 points / 64 B each) NOW — they land
    // while wave 0 runs the solve below.
    f32x16 B0, B1, B2;
    ISSUE(B0, pb);
    ISSUE(B1, pb + 64);
    ISSUE(B2, pb + 128);

    // ---- prologue: wave 0 redundantly solves prev iteration's (R,t) ----
    if (w == 0) {
        if (first) {
            if (l < 12) RtL[l] = (l == 0 || l == 4 || l == 8) ? 1.0f : 0.0f;
        } else {
            const float4* rp = (const float4*)(pprev + (b * 64 + l) * 16);
            float4 r0 = rp[0], r1 = rp[1], r2 = rp[2], r3 = rp[3];
            float sm[15] = { r0.x, r0.y, r0.z, r0.w, r1.x, r1.y, r1.z, r1.w,
                             r2.x, r2.y, r2.z, r2.w, r3.x, r3.y, r3.z };
            #pragma unroll
            for (int k = 0; k < 15; ++k) {
                float v = sm[k];
                v += __shfl_down(v, 32);
                v += __shfl_down(v, 16);
                v += __shfl_down(v, 8);
                v += __shfl_down(v, 4);
                v += __shfl_down(v, 2);
                v += __shfl_down(v, 1);
                sm[k] = v;
            }
            if (l == 0) kabsch_f32(sm, RtL);
        }
    }
    __syncthreads();

    // ---- transform own point; wave 1 persists it for the next iteration ----
    float px, py, pz;
    {
        const float* P = first ? src : S;
        float x = P[gsrc * 3 + 0];
        float y = P[gsrc * 3 + 1];
        float z = P[gsrc * 3 + 2];
        px = x * RtL[0] + y * RtL[3] + z * RtL[6] + RtL[9];
        py = x * RtL[1] + y * RtL[4] + z * RtL[7] + RtL[10];
        pz = x * RtL[2] + y * RtL[5] + z * RtL[8] + RtL[11];
    }
    if (w == 1) {
        S[gsrc * 3 + 0] = px;
        S[gsrc * 3 + 1] = py;
        S[gsrc * 3 + 2] = pz;
    }

    // ---- NN scan over the chunk, tgt data entirely in SGPRs ----
    // d = (|s|^2+1) - 2 s.t + |t|^2  (>0 -> u32-orderable); key packs the
    // top-20-bit quantized d with the 12-bit tgt index (first-min on ties).
    const float nx = -2.0f * px, ny = -2.0f * py, nz = -2.0f * pz;
    const float sxx1 = px * px + py * py + pz * pz + 1.0f;
    const int m0 = w << 9;
    unsigned int best = 0xFFFFFFFFu;

#define CONSUME(Bf, mb) do {                                              \
        _Pragma("unroll")                                                 \
        for (int j = 0; j < 4; ++j) {                                     \
            float tx = Bf[4 * j + 0], ty = Bf[4 * j + 1];                 \
            float tz = Bf[4 * j + 2], tw = Bf[4 * j + 3];                 \
            float d = fmaf(nx, tx, fmaf(ny, ty, fmaf(nz, tz, tw + sxx1)));\
            unsigned int key = (__float_as_uint(d) & 0xFFFFF000u) |       \
                               (unsigned int)((mb) + j);                  \
            best = best < key ? best : key;                               \
        }                                                                 \
    } while (0)

    // 128 groups of 4 points; depth-3 rotation, dummy reissues keep the
    // outstanding count at 3 so lgkmcnt(2) always means "oldest done".
    for (int it = 0; it < 42; ++it) {
        const int gb = it * 3;
        {
            SWAIT(B0, 2); CONSUME(B0, m0 + gb * 4);
            const int nxt = gb + 3 < 128 ? gb + 3 : 0;
            ISSUE(B0, pb + nxt * 64);
        }
        {
            SWAIT(B1, 2); CONSUME(B1, m0 + (gb + 1) * 4);
            const int nxt = gb + 4 < 128 ? gb + 4 : 0;
            ISSUE(B1, pb + nxt * 64);
        }
        {
            SWAIT(B2, 2); CONSUME(B2, m0 + (gb + 2) * 4);
            const int nxt = gb + 5 < 128 ? gb + 5 : 0;
            ISSUE(B2, pb + nxt * 64);
        }
    }
    // tail: groups 126, 127 live in B0, B1 (issued during it=41)
    SWAIT(B0, 2); CONSUME(B0, m0 + 126 * 4);
    SWAIT(B1, 1); CONSUME(B1, m0 + 127 * 4);
    // B2 holds a dummy reload of group 0; drained by the barrier below.
#undef CONSUME

    CK[w * 64 + l] = best;
    __syncthreads();

    // ---- wave 0: combine 8 chunk winners, gather match, 15-sum ----
    if (w == 0) {
        unsigned int kb = CK[l];
        #pragma unroll
        for (int k = 1; k < 8; ++k) {
            unsigned int kk = CK[k * 64 + l];
            kb = kk < kb ? kk : kb;
        }
        float4 mt = tb4[kb & 0xFFFu];             // global gather (L2-hot)
        const float tx = mt.x, ty = mt.y, tz = mt.z;

        float v[15];
        v[0]  = px;      v[1]  = py;      v[2]  = pz;
        v[3]  = tx;      v[4]  = ty;      v[5]  = tz;
        v[6]  = px * tx; v[7]  = px * ty; v[8]  = px * tz;
        v[9]  = py * tx; v[10] = py * ty; v[11] = py * tz;
        v[12] = pz * tx; v[13] = pz * ty; v[14] = pz * tz;
        #pragma unroll
        for (int k = 0; k < 15; ++k) {
            float s = v[k];
            s += __shfl_down(s, 32);
            s += __shfl_down(s, 16);
            s += __shfl_down(s, 8);
            s += __shfl_down(s, 4);
            s += __shfl_down(s, 2);
            s += __shfl_down(s, 1);
            v[k] = s;
        }
        if (l == 0) {
            float* pp = pout + blk * 16;
            #pragma unroll
            for (int k = 0; k < 15; ++k) pp[k] = v[k];
        }
    }
}

// Final: solve iteration-10's (R,t) (redundant per block), apply, write out.
// out layout: R [4,3,3] flat (36), t [4,3] flat (12), points [4,4096,3].
__global__ __launch_bounds__(256) void icp_final(
        const float* __restrict__ S,
        const float* __restrict__ plast,
        float* __restrict__ out) {
    __shared__ float RtL[12];
    const int bk  = blockIdx.x;
    const int tid = threadIdx.x;
    const int gid = bk * 256 + tid;               // 0..16383
    const int b   = gid >> 12;

    if (tid < 64) {
        const float4* rp = (const float4*)(plast + (b * 64 + tid) * 16);
        float4 r0 = rp[0], r1 = rp[1], r2 = rp[2], r3 = rp[3];
        float sm[15] = { r0.x, r0.y, r0.z, r0.w, r1.x, r1.y, r1.z, r1.w,
                         r2.x, r2.y, r2.z, r2.w, r3.x, r3.y, r3.z };
        #pragma unroll
        for (int k = 0; k < 15; ++k) {
            float v = sm[k];
            v += __shfl_down(v, 32);
            v += __shfl_down(v, 16);
            v += __shfl_down(v, 8);
            v += __shfl_down(v, 4);
            v += __shfl_down(v, 2);
            v += __shfl_down(v, 1);
            sm[k] = v;
        }
        if (tid == 0) kabsch_f32(sm, RtL);
    }
    __syncthreads();

    float x = S[gid * 3 + 0];
    float y = S[gid * 3 + 1];
    float z = S[gid * 3 + 2];
    out[48 + gid * 3 + 0] = x * RtL[0] + y * RtL[3] + z * RtL[6] + RtL[9];
    out[48 + gid * 3 + 1] = x * RtL[1] + y * RtL[4] + z * RtL[7] + RtL[10];
    out[48 + gid * 3 + 2] = x * RtL[2] + y * RtL[5] + z * RtL[8] + RtL[11];
    if ((bk & 15) == 0) {
        if (tid < 9) out[b * 9 + tid] = RtL[tid];
        if (tid < 3) out[36 + b * 3 + tid] = RtL[9 + tid];
    }
}

extern "C" void kernel_launch(void* const* d_in, const int* in_sizes, int n_in,
                              void* d_out, int out_size, void* d_ws, size_t ws_size,
                              hipStream_t stream) {
    const float* src = (const float*)d_in[0];
    const float* tgt = (const float*)d_in[1];
    float* out = (float*)d_out;

    float* W     = (float*)d_ws;
    float4* tgt4 = (float4*)W;         // 65536 floats
    float* S     = W + 65536;          // 49152 floats
    float* pA    = W + 65536 + 49152;  // 4096 floats (256 rows x 16)
    float* pB    = pA + 4096;          // 4096 floats
    float* bufs[2] = { pA, pB };

    init_tgt<<<64, 256, 0, stream>>>(tgt, tgt4);
    for (int k = 0; k < 10; ++k) {
        icp_scan<<<256, 512, 0, stream>>>(src, tgt4, S,
                                          bufs[(k + 1) & 1], bufs[k & 1],
                                          k == 0 ? 1 : 0);
    }
    icp_final<<<64, 256, 0, stream>>>(S, bufs[1], out);
}

// Round 6
// 235.817 us; speedup vs baseline: 2.4269x; 1.0798x over previous
//
#include <hip/hip_runtime.h>
#include <math.h>

#define NB 4
#define NP 4096   // src points per batch
#define MP 4096   // tgt points per batch

typedef float f32x16 __attribute__((ext_vector_type(16)));

// issue one 64 B scalar load (4 tgt points) into a 16-SGPR tuple
#define ISSUE(B, P) asm volatile("s_load_dwordx16 %0, %1, 0x0" \
                                 : "=s"(B) : "s"(P))
// wait until <=N scalar loads outstanding; tie to B so consumption can't hoist
#define SWAIT(B, N) asm volatile("s_waitcnt lgkmcnt(" #N ")" : "+s"(B))

// ---------------------------------------------------------------------------
// fp32 3x3 Kabsch from the 15 reduced sums (identical to R4/R5).
// ---------------------------------------------------------------------------
__device__ __forceinline__ void kabsch_f32(const float* s, float* RtL) {
    const float invN = 1.0f / (float)NP;
    float cs[3] = { s[0] * invN, s[1] * invN, s[2] * invN };
    float ct[3] = { s[3] * invN, s[4] * invN, s[5] * invN };
    float H[3][3];
    for (int d = 0; d < 3; ++d)
        for (int e = 0; e < 3; ++e)
            H[d][e] = s[6 + d * 3 + e] * invN - cs[d] * ct[e];

    float A[3][3];
    for (int i = 0; i < 3; ++i)
        for (int j = 0; j < 3; ++j)
            A[i][j] = H[0][i] * H[0][j] + H[1][i] * H[1][j] + H[2][i] * H[2][j];

    float V[3][3] = {{1, 0, 0}, {0, 1, 0}, {0, 0, 1}};
    for (int sweep = 0; sweep < 10; ++sweep) {
        float off = A[0][1] * A[0][1] + A[0][2] * A[0][2] + A[1][2] * A[1][2];
        if (off < 1e-16f) break;
        for (int pi = 0; pi < 3; ++pi) {
            const int p = (pi == 2) ? 1 : 0;
            const int q = (pi == 0) ? 1 : 2;
            float apq = A[p][q];
            if (fabsf(apq) < 1e-30f) continue;
            float theta = (A[q][q] - A[p][p]) / (2.0f * apq);
            float t = 1.0f / (fabsf(theta) + sqrtf(1.0f + theta * theta));
            if (theta < 0.0f) t = -t;
            float cth = 1.0f / sqrtf(1.0f + t * t);
            float sth = t * cth;
            float App = A[p][p], Aqq = A[q][q];
            A[p][p] = App - t * apq;
            A[q][q] = Aqq + t * apq;
            A[p][q] = A[q][p] = 0.0f;
            const int r = 3 - p - q;
            float Apr = A[p][r], Aqr = A[q][r];
            A[p][r] = A[r][p] = cth * Apr - sth * Aqr;
            A[q][r] = A[r][q] = sth * Apr + cth * Aqr;
            for (int i = 0; i < 3; ++i) {
                float Vip = V[i][p], Viq = V[i][q];
                V[i][p] = cth * Vip - sth * Viq;
                V[i][q] = sth * Vip + cth * Viq;
            }
        }
    }
    float lam[3] = { A[0][0], A[1][1], A[2][2] };
    for (int i = 0; i < 2; ++i)
        for (int j = i + 1; j < 3; ++j)
            if (lam[j] > lam[i]) {
                float tl = lam[i]; lam[i] = lam[j]; lam[j] = tl;
                for (int k = 0; k < 3; ++k) {
                    float tv = V[k][i]; V[k][i] = V[k][j]; V[k][j] = tv;
                }
            }

    float U[3][3];
    for (int k = 0; k < 3; ++k) {
        float w0 = H[0][0] * V[0][k] + H[0][1] * V[1][k] + H[0][2] * V[2][k];
        float w1 = H[1][0] * V[0][k] + H[1][1] * V[1][k] + H[1][2] * V[2][k];
        float w2 = H[2][0] * V[0][k] + H[2][1] * V[1][k] + H[2][2] * V[2][k];
        float nrm = sqrtf(w0 * w0 + w1 * w1 + w2 * w2);
        if (nrm > 1e-20f) {
            U[0][k] = w0 / nrm; U[1][k] = w1 / nrm; U[2][k] = w2 / nrm;
        } else {
            U[0][k] = U[1][0] * U[2][1] - U[2][0] * U[1][1];
            U[1][k] = U[2][0] * U[0][1] - U[0][0] * U[2][1];
            U[2][k] = U[0][0] * U[1][1] - U[1][0] * U[0][1];
        }
    }

    float detH = H[0][0] * (H[1][1] * H[2][2] - H[1][2] * H[2][1])
               - H[0][1] * (H[1][0] * H[2][2] - H[1][2] * H[2][0])
               + H[0][2] * (H[1][0] * H[2][1] - H[1][1] * H[2][0]);
    float sgn = (detH < 0.0f) ? -1.0f : 1.0f;

    float R[3][3];
    for (int i = 0; i < 3; ++i)
        for (int j = 0; j < 3; ++j)
            R[i][j] = V[i][0] * U[j][0] + V[i][1] * U[j][1] + sgn * V[i][2] * U[j][2];
    float tv[3];
    for (int i = 0; i < 3; ++i)
        tv[i] = ct[i] - (R[i][0] * cs[0] + R[i][1] * cs[1] + R[i][2] * cs[2]);

    for (int i = 0; i < 3; ++i)
        for (int j = 0; j < 3; ++j)
            RtL[i * 3 + j] = R[i][j];
    for (int i = 0; i < 3; ++i) RtL[9 + i] = tv[i];
}

__global__ __launch_bounds__(256) void init_tgt(const float* __restrict__ tgt,
                                                float4* __restrict__ tgt4) {
    int j = blockIdx.x * 256 + threadIdx.x;       // 0..16383
    float x = tgt[j * 3 + 0];
    float y = tgt[j * 3 + 1];
    float z = tgt[j * 3 + 2];
    tgt4[j] = make_float4(x, y, z, x * x + y * y + z * z);
}

// ---------------------------------------------------------------------------
// One ICP iteration per dispatch. 256 blocks (batch b = blk>>6, src-group
// g = blk&63), 1024 threads = 16 waves (4 waves/SIMD for scalar-load latency
// hiding); lane l of every wave owns src point l of the group; wave w scans
// tgt chunk [w*256, w*256+256) streamed through 3 rotating 16-SGPR buffers
// via s_load_dwordx16 (wave-uniform data -> scalar pipe, zero LDS/VMEM in
// the loop). Prefetch issued before the prologue barrier so the loads fly
// during the redundant fp32 Kabsch solve.
// ---------------------------------------------------------------------------
__global__ __launch_bounds__(1024) void icp_scan(
        const float* __restrict__ src,
        const float4* __restrict__ tgt4,
        float* __restrict__ S,            // [NB*NP*3] transformed points
        const float* __restrict__ pprev,  // [256][16] prev partials
        float* __restrict__ pout,         // [256][16] this iter's partials
        int first) {
    __shared__ unsigned int CK[1024];
    __shared__ float RtL[12];

    const int blk = blockIdx.x;
    const int b   = blk >> 6;
    const int g   = blk & 63;
    const int tid = threadIdx.x;
    const int w   = tid >> 6;             // wave 0..15
    const int l   = tid & 63;
    const int gsrc = b * NP + g * 64 + l;

    // wave-uniform base of this wave's 256-point chunk (bytes)
    const float4* tb4 = tgt4 + b * MP;
    unsigned chunkOff = __builtin_amdgcn_readfirstlane((unsigned)(w << 8) * 16u);
    const char* pb = (const char*)tb4 + chunkOff;

    // prefetch the first 3 groups (4 points / 64 B each) NOW — they land
    // while wave 0 runs the solve below.
    f32x16 B0, B1, B2;
    ISSUE(B0, pb);
    ISSUE(B1, pb + 64);
    ISSUE(B2, pb + 128);

    // ---- prologue: wave 0 redundantly solves prev iteration's (R,t) ----
    if (w == 0) {
        if (first) {
            if (l < 12) RtL[l] = (l == 0 || l == 4 || l == 8) ? 1.0f : 0.0f;
        } else {
            const float4* rp = (const float4*)(pprev + (b * 64 + l) * 16);
            float4 r0 = rp[0], r1 = rp[1], r2 = rp[2], r3 = rp[3];
            float sm[15] = { r0.x, r0.y, r0.z, r0.w, r1.x, r1.y, r1.z, r1.w,
                             r2.x, r2.y, r2.z, r2.w, r3.x, r3.y, r3.z };
            #pragma unroll
            for (int k = 0; k < 15; ++k) {
                float v = sm[k];
                v += __shfl_down(v, 32);
                v += __shfl_down(v, 16);
                v += __shfl_down(v, 8);
                v += __shfl_down(v, 4);
                v += __shfl_down(v, 2);
                v += __shfl_down(v, 1);
                sm[k] = v;
            }
            if (l == 0) kabsch_f32(sm, RtL);
        }
    }
    __syncthreads();

    // ---- transform own point; wave 1 persists it for the next iteration ----
    float px, py, pz;
    {
        const float* P = first ? src : S;
        float x = P[gsrc * 3 + 0];
        float y = P[gsrc * 3 + 1];
        float z = P[gsrc * 3 + 2];
        px = x * RtL[0] + y * RtL[3] + z * RtL[6] + RtL[9];
        py = x * RtL[1] + y * RtL[4] + z * RtL[7] + RtL[10];
        pz = x * RtL[2] + y * RtL[5] + z * RtL[8] + RtL[11];
    }
    if (w == 1) {
        S[gsrc * 3 + 0] = px;
        S[gsrc * 3 + 1] = py;
        S[gsrc * 3 + 2] = pz;
    }

    // ---- NN scan over the chunk, tgt data entirely in SGPRs ----
    // d = (|s|^2+1) - 2 s.t + |t|^2  (>0, u32-orderable); key packs the
    // top-20-bit quantized d with the 12-bit tgt index (first-min on ties).
    const float nx = -2.0f * px, ny = -2.0f * py, nz = -2.0f * pz;
    const float sxx1 = px * px + py * py + pz * pz + 1.0f;
    const int m0 = w << 8;
    unsigned int best = 0xFFFFFFFFu;

#define CONSUME(Bf, mb) do {                                              \
        _Pragma("unroll")                                                 \
        for (int j = 0; j < 4; ++j) {                                     \
            float tx = Bf[4 * j + 0], ty = Bf[4 * j + 1];                 \
            float tz = Bf[4 * j + 2], tw = Bf[4 * j + 3];                 \
            float d = fmaf(nx, tx, fmaf(ny, ty, fmaf(nz, tz, tw + sxx1)));\
            unsigned int key = (__float_as_uint(d) & 0xFFFFF000u) |       \
                               (unsigned int)((mb) + j);                  \
            best = best < key ? best : key;                               \
        }                                                                 \
    } while (0)

    // 64 groups of 4 points; depth-3 rotation, dummy reissues keep the
    // outstanding count at 3 so lgkmcnt(2) always means "oldest done".
    for (int it = 0; it < 21; ++it) {
        const int gb = it * 3;
        {
            SWAIT(B0, 2); CONSUME(B0, m0 + gb * 4);
            const int nxt = gb + 3 < 64 ? gb + 3 : 0;
            ISSUE(B0, pb + nxt * 64);
        }
        {
            SWAIT(B1, 2); CONSUME(B1, m0 + (gb + 1) * 4);
            const int nxt = gb + 4 < 64 ? gb + 4 : 0;
            ISSUE(B1, pb + nxt * 64);
        }
        {
            SWAIT(B2, 2); CONSUME(B2, m0 + (gb + 2) * 4);
            const int nxt = gb + 5 < 64 ? gb + 5 : 0;
            ISSUE(B2, pb + nxt * 64);
        }
    }
    // tail: group 63 lives in B0 (issued during it=20); B1/B2 hold dummies
    SWAIT(B0, 2); CONSUME(B0, m0 + 63 * 4);
#undef CONSUME

    CK[w * 64 + l] = best;
    __syncthreads();

    // ---- wave 0: combine 16 chunk winners, gather match, 15-sum ----
    if (w == 0) {
        unsigned int kb = CK[l];
        #pragma unroll
        for (int k = 1; k < 16; ++k) {
            unsigned int kk = CK[k * 64 + l];
            kb = kk < kb ? kk : kb;
        }
        float4 mt = tb4[kb & 0xFFFu];             // global gather (L2-hot)
        const float tx = mt.x, ty = mt.y, tz = mt.z;

        float v[15];
        v[0]  = px;      v[1]  = py;      v[2]  = pz;
        v[3]  = tx;      v[4]  = ty;      v[5]  = tz;
        v[6]  = px * tx; v[7]  = px * ty; v[8]  = px * tz;
        v[9]  = py * tx; v[10] = py * ty; v[11] = py * tz;
        v[12] = pz * tx; v[13] = pz * ty; v[14] = pz * tz;
        #pragma unroll
        for (int k = 0; k < 15; ++k) {
            float s = v[k];
            s += __shfl_down(s, 32);
            s += __shfl_down(s, 16);
            s += __shfl_down(s, 8);
            s += __shfl_down(s, 4);
            s += __shfl_down(s, 2);
            s += __shfl_down(s, 1);
            v[k] = s;
        }
        if (l == 0) {
            float* pp = pout + blk * 16;
            #pragma unroll
            for (int k = 0; k < 15; ++k) pp[k] = v[k];
        }
    }
}

// Final: solve iteration-10's (R,t) (redundant per block), apply, write out.
// out layout: R [4,3,3] flat (36), t [4,3] flat (12), points [4,4096,3].
__global__ __launch_bounds__(256) void icp_final(
        const float* __restrict__ S,
        const float* __restrict__ plast,
        float* __restrict__ out) {
    __shared__ float RtL[12];
    const int bk  = blockIdx.x;
    const int tid = threadIdx.x;
    const int gid = bk * 256 + tid;               // 0..16383
    const int b   = gid >> 12;

    if (tid < 64) {
        const float4* rp = (const float4*)(plast + (b * 64 + tid) * 16);
        float4 r0 = rp[0], r1 = rp[1], r2 = rp[2], r3 = rp[3];
        float sm[15] = { r0.x, r0.y, r0.z, r0.w, r1.x, r1.y, r1.z, r1.w,
                         r2.x, r2.y, r2.z, r2.w, r3.x, r3.y, r3.z };
        #pragma unroll
        for (int k = 0; k < 15; ++k) {
            float v = sm[k];
            v += __shfl_down(v, 32);
            v += __shfl_down(v, 16);
            v += __shfl_down(v, 8);
            v += __shfl_down(v, 4);
            v += __shfl_down(v, 2);
            v += __shfl_down(v, 1);
            sm[k] = v;
        }
        if (tid == 0) kabsch_f32(sm, RtL);
    }
    __syncthreads();

    float x = S[gid * 3 + 0];
    float y = S[gid * 3 + 1];
    float z = S[gid * 3 + 2];
    out[48 + gid * 3 + 0] = x * RtL[0] + y * RtL[3] + z * RtL[6] + RtL[9];
    out[48 + gid * 3 + 1] = x * RtL[1] + y * RtL[4] + z * RtL[7] + RtL[10];
    out[48 + gid * 3 + 2] = x * RtL[2] + y * RtL[5] + z * RtL[8] + RtL[11];
    if ((bk & 15) == 0) {
        if (tid < 9) out[b * 9 + tid] = RtL[tid];
        if (tid < 3) out[36 + b * 3 + tid] = RtL[9 + tid];
    }
}

extern "C" void kernel_launch(void* const* d_in, const int* in_sizes, int n_in,
                              void* d_out, int out_size, void* d_ws, size_t ws_size,
                              hipStream_t stream) {
    const float* src = (const float*)d_in[0];
    const float* tgt = (const float*)d_in[1];
    float* out = (float*)d_out;

    float* W     = (float*)d_ws;
    float4* tgt4 = (float4*)W;         // 65536 floats
    float* S     = W + 65536;          // 49152 floats
    float* pA    = W + 65536 + 49152;  // 4096 floats (256 rows x 16)
    float* pB    = pA + 4096;          // 4096 floats
    float* bufs[2] = { pA, pB };

    init_tgt<<<64, 256, 0, stream>>>(tgt, tgt4);
    for (int k = 0; k < 10; ++k) {
        icp_scan<<<256, 1024, 0, stream>>>(src, tgt4, S,
                                           bufs[(k + 1) & 1], bufs[k & 1],
                                           k == 0 ? 1 : 0);
    }
    icp_final<<<64, 256, 0, stream>>>(S, bufs[1], out);
}